// Round 13
// baseline (865.154 us; speedup 1.0000x reference)
//
#include <hip/hip_runtime.h>
#include <cstdint>
#include <cstddef>

#define XF 10
#define NF 100
#define HF 200
#define BSHIFT 8
#define NBLK_G 512   // blocks for count/scatter passes
#define MAXBK 512    // max dst buckets (N <= 131072)
#define RCH 4        // readout chunks per graph

typedef _Float16 f16x8 __attribute__((ext_vector_type(8)));
typedef _Float16 h2 __attribute__((ext_vector_type(2)));
typedef float f32x4 __attribute__((ext_vector_type(4)));

static __device__ __forceinline__ float bn_scale(float g) {
    return g * 0.9999950000374997f; // 1/sqrt(1 + 1e-5)
}

// ---------------- CSR build: radix partition by dst, no global data atomics ----
__global__ __launch_bounds__(256) void csr_count_kernel(const int* __restrict__ eidx,
                                                        int* __restrict__ bmat,
                                                        int E, int nbk, int epb) {
    __shared__ int hist[MAXBK];
    for (int j = threadIdx.x; j < nbk; j += 256) hist[j] = 0;
    __syncthreads();
    int base = blockIdx.x * epb;
    int end = base + epb; if (end > E) end = E;
    for (int e = base + threadIdx.x; e < end; e += 256) {
        int d = eidx[E + e];
        atomicAdd(&hist[d >> BSHIFT], 1);
    }
    __syncthreads();
    for (int j = threadIdx.x; j < nbk; j += 256)
        bmat[(size_t)j * NBLK_G + blockIdx.x] = hist[j];
}

// chunked exclusive scan of bmat (in place), 1024 elems/chunk; blocksum = chunk totals
__global__ __launch_bounds__(256) void scan1x_kernel(int* __restrict__ a,
                                                     int* __restrict__ blocksum, int n) {
    __shared__ int s[256];
    int t = threadIdx.x;
    int base = blockIdx.x * 1024 + t * 4;
    int v[4]; int tot = 0;
#pragma unroll
    for (int i = 0; i < 4; ++i) {
        v[i] = (base + i < n) ? a[base + i] : 0;
        tot += v[i];
    }
    s[t] = tot;
    __syncthreads();
    for (int off = 1; off < 256; off <<= 1) {
        int add = (t >= off) ? s[t - off] : 0;
        __syncthreads();
        s[t] += add;
        __syncthreads();
    }
    int run = s[t] - tot; // exclusive within chunk
#pragma unroll
    for (int i = 0; i < 4; ++i) {
        if (base + i < n) a[base + i] = run;
        run += v[i];
    }
    if (t == 255) blocksum[blockIdx.x] = s[255];
}

// generic single-block exclusive scan for n<=1024 (strided; in-place safe)
__global__ void small_scan_kernel(const int* __restrict__ in, int in_stride,
                                  int* __restrict__ cur, int cur_stride,
                                  int* __restrict__ indptr, int n) {
    __shared__ int s[256];
    int t = threadIdx.x;
    int base = t * 4;
    int v[4]; int tot = 0;
#pragma unroll
    for (int i = 0; i < 4; ++i) {
        v[i] = (base + i < n) ? in[(base + i) * in_stride] : 0;
        tot += v[i];
    }
    s[t] = tot;
    __syncthreads();
    for (int off = 1; off < 256; off <<= 1) {
        int add = (t >= off) ? s[t - off] : 0;
        __syncthreads();
        s[t] += add;
        __syncthreads();
    }
    int run = s[t] - tot;
#pragma unroll
    for (int i = 0; i < 4; ++i) {
        if (base + i < n) {
            cur[(base + i) * cur_stride] = run;
            run += v[i];
            if (indptr) indptr[base + i + 1] = run;
        }
    }
    if (t == 0 && indptr) indptr[0] = 0;
}

// scatter packed (src | dlocal<<24); cursor = bmat chunk-scan + blocksum offset
__global__ __launch_bounds__(256) void csr_scatter_kernel(const int* __restrict__ eidx,
                                                          const int* __restrict__ bmat,
                                                          const int* __restrict__ blocksum,
                                                          int* __restrict__ packed,
                                                          int E, int nbk, int epb) {
    __shared__ int cur[MAXBK];
    for (int j = threadIdx.x; j < nbk; j += 256) {
        size_t idx = (size_t)j * NBLK_G + blockIdx.x;
        cur[j] = bmat[idx] + blocksum[idx >> 10];
    }
    __syncthreads();
    int base = blockIdx.x * epb;
    int end = base + epb; if (end > E) end = E;
    for (int e = base + threadIdx.x; e < end; e += 256) {
        int s = eidx[e];
        int d = eidx[E + e];
        int p = atomicAdd(&cur[d >> BSHIFT], 1);
        packed[p] = s | ((d & 255) << 24);
    }
}

// one block per bucket -> indptr + esrc (LDS count/scan/cursors only)
__global__ __launch_bounds__(256) void csr_finalize_kernel(const int* __restrict__ bmat,
                                                           const int* __restrict__ blocksum,
                                                           const int* __restrict__ packed,
                                                           int* __restrict__ indptr,
                                                           int* __restrict__ esrc,
                                                           int E, int nbk, int n) {
    __shared__ int cnt[256];
    __shared__ int s[256];
    __shared__ int cur[256];
    int b = blockIdx.x;
    int t = threadIdx.x;
    size_t i0 = (size_t)b * NBLK_G;
    int ebeg = bmat[i0] + blocksum[i0 >> 10];
    int eend = E;
    if (b + 1 < nbk) {
        size_t i1 = (size_t)(b + 1) * NBLK_G;
        eend = bmat[i1] + blocksum[i1 >> 10];
    }
    cnt[t] = 0;
    __syncthreads();
    for (int i = ebeg + t; i < eend; i += 256)
        atomicAdd(&cnt[((unsigned)packed[i]) >> 24], 1);
    __syncthreads();
    int tot = cnt[t];
    s[t] = tot;
    __syncthreads();
    for (int off = 1; off < 256; off <<= 1) {
        int add = (t >= off) ? s[t - off] : 0;
        __syncthreads();
        s[t] += add;
        __syncthreads();
    }
    int off_ex = s[t] - tot; // exclusive
    int node = (b << BSHIFT) + t;
    if (node < n) indptr[node] = ebeg + off_ex;
    if (b == nbk - 1 && t == 0) indptr[n] = E;
    cur[t] = ebeg + off_ex;
    __syncthreads();
    for (int i = ebeg + t; i < eend; i += 256) {
        int p = packed[i];
        int pos = atomicAdd(&cur[((unsigned)p) >> 24], 1);
        esrc[pos] = p & 0xFFFFFF;
    }
}

// batch-CSR: per-graph node lists
__global__ __launch_bounds__(256) void gcnt_kernel(const int* __restrict__ batch,
                                                   int* __restrict__ gcount, int n) {
    int i = blockIdx.x * 256 + threadIdx.x;
    if (i < n) atomicAdd(&gcount[batch[i]], 1);
}

__global__ __launch_bounds__(256) void gfill_kernel(const int* __restrict__ batch,
                                                    int* __restrict__ gcur,
                                                    int* __restrict__ gnodes, int n) {
    int i = blockIdx.x * 256 + threadIdx.x;
    if (i >= n) return;
    int g = batch[i];
    int p = atomicAdd(&gcur[g], 1);
    gnodes[p] = i;
}

// ---------------- weight conversion to fp16, K padded ----------------
struct WArgs {
    const float* src[6];
    _Float16* dst[6];
};
__global__ __launch_bounds__(256) void wconv_kernel(WArgs wa) {
    int w = blockIdx.y;
    int idx = blockIdx.x * 256 + threadIdx.x; // < 32768
    int J, K, j, k;
    if (w < 3) { J = 200; K = 100; j = idx >> 7; k = idx & 127; }
    else       { J = 100; K = 200; j = idx >> 8; k = idx & 255; }
    float v = (j < J && k < K) ? wa.src[w][j * K + k] : 0.f;
    wa.dst[w][idx] = (_Float16)v;
}

// ---------------- layer-1 input linear (10 -> 100) -> fp16, stride 128 ---------
__global__ __launch_bounds__(256) void lin10_kernel(const float* __restrict__ x,
                                                    const float* __restrict__ sw,
                                                    const float* __restrict__ sb,
                                                    const float* __restrict__ dw,
                                                    const float* __restrict__ db,
                                                    _Float16* __restrict__ h16,
                                                    _Float16* __restrict__ xd16, int n_nodes) {
    int t = threadIdx.x;
    int slot = t >> 6, lane = t & 63;
    bool act = lane < 50;
    int f0 = 2 * lane, f1 = f0 + 1;
    float ws0[XF], ws1[XF], wd0[XF], wd1[XF];
    float bs0 = 0.f, bs1 = 0.f, bd0 = 0.f, bd1 = 0.f;
    if (act) {
#pragma unroll
        for (int k = 0; k < XF; ++k) {
            ws0[k] = sw[f0 * XF + k]; ws1[k] = sw[f1 * XF + k];
            wd0[k] = dw[f0 * XF + k]; wd1[k] = dw[f1 * XF + k];
        }
        bs0 = sb[f0]; bs1 = sb[f1]; bd0 = db[f0]; bd1 = db[f1];
    }
    for (int it = 0; it < 16; ++it) {
        int n = blockIdx.x * 64 + it * 4 + slot;
        if (n >= n_nodes) continue;
        float a0 = bs0, a1 = bs1, b0 = bd0, b1 = bd1;
        if (act) {
            const float2* xp = (const float2*)(x + (size_t)n * XF);
            float xv[XF];
#pragma unroll
            for (int k = 0; k < 5; ++k) { float2 v = xp[k]; xv[2 * k] = v.x; xv[2 * k + 1] = v.y; }
#pragma unroll
            for (int k = 0; k < XF; ++k) {
                a0 = fmaf(xv[k], ws0[k], a0);
                a1 = fmaf(xv[k], ws1[k], a1);
                b0 = fmaf(xv[k], wd0[k], b0);
                b1 = fmaf(xv[k], wd1[k], b1);
            }
        } else { a0 = a1 = b0 = b1 = 0.f; }
        ((h2*)(h16 + (size_t)n * 128))[lane] = (h2){(_Float16)a0, (_Float16)a1};
        ((h2*)(xd16 + (size_t)n * 128))[lane] = (h2){(_Float16)b0, (_Float16)b1};
    }
}

// ---------------- softmax aggregation: 2 waves per node ----------------
// Max-free softmax (e = exp2(a*log2e - 40)); partials (d,s) are plain sums
// under the uniform shift, so two waves split a node's edge list stride-2 and
// combine via LDS. Halves the serial chain (deg~16 -> ~8 = one prefetch group).
// RELU=false for layers 2-3 (input already post-ReLU).
template <bool RELU>
__global__ __launch_bounds__(256) void agg_kernel(const _Float16* __restrict__ h16,
                                                  const _Float16* __restrict__ xd16,
                                                  const int* __restrict__ indptr,
                                                  const int* __restrict__ esrc,
                                                  _Float16* __restrict__ c16, int n_nodes) {
    __shared__ float4 part[4][64];
    int wave = threadIdx.x >> 6;
    int lane = threadIdx.x & 63;
    int half = wave & 1;
    int n = blockIdx.x * 2 + (wave >> 1);
    int ln = (lane < 50) ? lane : 0;
    const h2* hb = (const h2*)h16;
    const float L2E = 1.44269504088896f;
    float d0 = 0.f, d1 = 0.f, s0 = 0.f, s1 = 0.f;
    if (n < n_nodes) {
        int beg = __builtin_amdgcn_readfirstlane(indptr[n]);
        int end = __builtin_amdgcn_readfirstlane(indptr[n + 1]);
        int deg = end - beg;
        int cnt = (deg - half + 1) >> 1; // my edges: beg+half, +2, ...
        if (cnt > 0) {
            int base = beg + half;
            h2 va[8], vb[8];
#pragma unroll
            for (int k = 0; k < 8; ++k) {
                int j = (k < cnt) ? k : cnt - 1;
                unsigned sidx = (unsigned)esrc[base + 2 * j];
                va[k] = hb[(size_t)sidx * 64 + ln];
            }
            for (int r = 0; r < cnt; r += 8) {
                if (r + 8 < cnt) {
#pragma unroll
                    for (int k = 0; k < 8; ++k) {
                        int j = (r + 8 + k < cnt) ? r + 8 + k : cnt - 1;
                        unsigned sidx = (unsigned)esrc[base + 2 * j];
                        vb[k] = hb[(size_t)sidx * 64 + ln];
                    }
                }
                int km = cnt - r; if (km > 8) km = 8;
#pragma unroll
                for (int k = 0; k < 8; ++k) {
                    if (k < km) {
                        float a0 = (float)va[k].x;
                        float a1 = (float)va[k].y;
                        if (RELU) { a0 = fmaxf(a0, 0.f); a1 = fmaxf(a1, 0.f); }
                        a0 += 1e-7f; a1 += 1e-7f;
                        float e0 = __builtin_amdgcn_exp2f(fmaf(a0, L2E, -40.f));
                        float e1 = __builtin_amdgcn_exp2f(fmaf(a1, L2E, -40.f));
                        d0 += e0; s0 = fmaf(e0, a0, s0);
                        d1 += e1; s1 = fmaf(e1, a1, s1);
                    }
                }
#pragma unroll
                for (int k = 0; k < 8; ++k) va[k] = vb[k];
            }
        }
    }
    part[wave][lane] = make_float4(d0, d1, s0, s1);
    __syncthreads();
    if (half == 0 && n < n_nodes) {
        float4 o = part[wave | 1][lane];
        d0 += o.x; d1 += o.y; s0 += o.z; s1 += o.w;
        const float EPS = 9.094947e-29f; // 1e-16 * 2^-40
        float g0 = s0 / (d0 + EPS);
        float g1 = s1 / (d1 + EPS);
        float o0 = 0.f, o1 = 0.f;
        if (lane < 50) {
            h2 xv = ((const h2*)(xd16 + (size_t)n * 128))[lane];
            o0 = g0 + (float)xv.x;
            o1 = g1 + (float)xv.y;
        }
        ((h2*)(c16 + (size_t)n * 128))[lane] = (h2){(_Float16)o0, (_Float16)o1};
    }
}

// ---------------- fused MLP: h = relu(BN(C@W1^T+b1)) @ W2^T + b2, relu -------
__global__ __launch_bounds__(256, 3) void mlp_fused_kernel(const _Float16* __restrict__ A,
                                                           const _Float16* __restrict__ W1,
                                                           const float* __restrict__ b1v,
                                                           const float* __restrict__ g1v,
                                                           const float* __restrict__ be1v,
                                                           const _Float16* __restrict__ W2,
                                                           const float* __restrict__ b2v,
                                                           _Float16* __restrict__ out16,
                                                           int M) {
    __shared__ _Float16 hh[64][264];
    int wave = threadIdx.x >> 6;
    int lane = threadIdx.x & 63;
    int l15 = lane & 15, quad = lane >> 4;
    long m0 = (long)blockIdx.x * 64;

    // stage 1: HH[64 x 256], wave covers cols [wave*64, wave*64+64)
    const _Float16* aptr = A + (m0 + l15) * 128 + quad * 8;
    const _Float16* w1p  = W1 + (size_t)(wave * 64 + l15) * 128 + quad * 8;
    f32x4 acc[4][4] = {};
#pragma unroll 2
    for (int ks = 0; ks < 4; ++ks) {
        f16x8 bfr[4], afr[4];
#pragma unroll
        for (int ct = 0; ct < 4; ++ct) bfr[ct] = *(const f16x8*)(w1p + (size_t)ct * 16 * 128 + ks * 32);
#pragma unroll
        for (int i = 0; i < 4; ++i) afr[i] = *(const f16x8*)(aptr + (size_t)i * 16 * 128 + ks * 32);
#pragma unroll
        for (int i = 0; i < 4; ++i)
#pragma unroll
            for (int ct = 0; ct < 4; ++ct)
                acc[i][ct] = __builtin_amdgcn_mfma_f32_16x16x32_f16(afr[i], bfr[ct], acc[i][ct], 0, 0, 0);
    }
#pragma unroll
    for (int ct = 0; ct < 4; ++ct) {
        int col = wave * 64 + ct * 16 + l15;
        bool cv = col < HF;
        float bi = cv ? b1v[col] : 0.f;
        float gm = cv ? bn_scale(g1v[col]) : 0.f;
        float bt = cv ? be1v[col] : 0.f;
#pragma unroll
        for (int i = 0; i < 4; ++i)
#pragma unroll
            for (int r = 0; r < 4; ++r) {
                float v = fmaxf((acc[i][ct][r] + bi) * gm + bt, 0.f);
                hh[i * 16 + quad * 4 + r][col] = (_Float16)v;
            }
    }
    __syncthreads();

    // stage 2: out[64 x 128], wave covers cols [wave*32, wave*32+32)
    const _Float16* w2p = W2 + (size_t)(wave * 32 + l15) * 256 + quad * 8;
    f32x4 o[4][2] = {};
#pragma unroll 2
    for (int ks = 0; ks < 8; ++ks) {
        f16x8 bfr[2], afr[4];
#pragma unroll
        for (int ct = 0; ct < 2; ++ct) bfr[ct] = *(const f16x8*)(w2p + (size_t)ct * 16 * 256 + ks * 32);
#pragma unroll
        for (int i = 0; i < 4; ++i) afr[i] = *(const f16x8*)(&hh[i * 16 + l15][quad * 8 + ks * 32]);
#pragma unroll
        for (int i = 0; i < 4; ++i)
#pragma unroll
            for (int ct = 0; ct < 2; ++ct)
                o[i][ct] = __builtin_amdgcn_mfma_f32_16x16x32_f16(afr[i], bfr[ct], o[i][ct], 0, 0, 0);
    }
#pragma unroll
    for (int ct = 0; ct < 2; ++ct) {
        int col = wave * 32 + ct * 16 + l15;
        bool cv = col < NF;
        float bi = cv ? b2v[col] : 0.f;
#pragma unroll
        for (int i = 0; i < 4; ++i)
#pragma unroll
            for (int r = 0; r < 4; ++r) {
                long row = m0 + i * 16 + quad * 4 + r;
                float v = fmaxf(o[i][ct][r] + bi, 0.f);
                if (!cv) v = 0.f;
                if (row < M) out16[row * 128 + col] = (_Float16)v;
            }
    }
}

// ---------------- readout: per-graph gather, 4 chunks/graph -------------------
__global__ __launch_bounds__(256) void readout2_kernel(const _Float16* __restrict__ h16,
                                                       const int* __restrict__ gindptr,
                                                       const int* __restrict__ gnodes,
                                                       float* __restrict__ sumpart,
                                                       float* __restrict__ maxpart, int G) {
    __shared__ float ls[4][128];
    __shared__ float lm[4][128];
    int g = blockIdx.x, ch = blockIdx.y;
    int wave = threadIdx.x >> 6;
    int lane = threadIdx.x & 63;
    int ln = (lane < 50) ? lane : 0;
    int beg = gindptr[g], end = gindptr[g + 1];
    const h2* hb = (const h2*)h16;
    float s0 = 0.f, s1 = 0.f, m0 = 0.f, m1 = 0.f;
    int i = beg + ch * 4 + wave;
    int nd = (i < end) ? gnodes[i] : 0;
    for (; i < end; i += 16) {
        int ndn = (i + 16 < end) ? gnodes[i + 16] : 0;
        h2 v = hb[(size_t)nd * 64 + ln];
        float v0 = (float)v.x, v1 = (float)v.y;
        s0 += v0; s1 += v1;
        m0 = fmaxf(m0, v0); m1 = fmaxf(m1, v1);
        nd = ndn;
    }
    ls[wave][2 * lane] = s0; ls[wave][2 * lane + 1] = s1;
    lm[wave][2 * lane] = m0; lm[wave][2 * lane + 1] = m1;
    __syncthreads();
    int f = threadIdx.x;
    if (f < NF) {
        float ss = ls[0][f] + ls[1][f] + ls[2][f] + ls[3][f];
        float mm = fmaxf(fmaxf(lm[0][f], lm[1][f]), fmaxf(lm[2][f], lm[3][f]));
        sumpart[((size_t)ch * G + g) * NF + f] = ss;
        maxpart[((size_t)ch * G + g) * NF + f] = mm;
    }
}

// ---------------- head: combine partials + encode + fc1 + classifier ----------
__global__ __launch_bounds__(256) void head_kernel(const float* __restrict__ rbuf,
                                                   const int* __restrict__ gindptr,
                                                   const float* __restrict__ fc1w,
                                                   const float* __restrict__ fc1b,
                                                   const float* __restrict__ clsw,
                                                   const float* __restrict__ clsb,
                                                   float* __restrict__ out, int G) {
    __shared__ float enc[HF];
    __shared__ float z[NF];
    int g = blockIdx.x;
    int t = threadIdx.x;
    float ic = 1.f / fmaxf((float)(gindptr[g + 1] - gindptr[g]), 1.f);
    if (t < HF) {
        float e = 0.f;
        if (t < NF) {
#pragma unroll
            for (int l = 0; l < 3; ++l) {
                float s = 0.f;
#pragma unroll
                for (int ch = 0; ch < RCH; ++ch)
                    s += rbuf[(((size_t)(l * 2) * RCH + ch) * G + g) * NF + t];
                e += fmaxf(s * ic, 0.f);
            }
        } else {
            int f = t - NF;
#pragma unroll
            for (int l = 0; l < 3; ++l) {
                float mm = 0.f;
#pragma unroll
                for (int ch = 0; ch < RCH; ++ch)
                    mm = fmaxf(mm, rbuf[(((size_t)(l * 2 + 1) * RCH + ch) * G + g) * NF + f]);
                e += fmaxf(mm, 0.f);
            }
        }
        enc[t] = e;
        out[G * 2 + (size_t)g * HF + t] = e;
    }
    __syncthreads();
    if (t < NF) {
        float a = fc1b[t];
        for (int k = 0; k < HF; ++k) a += enc[k] * fc1w[t * HF + k];
        z[t] = fmaxf(a, 0.f);
    }
    __syncthreads();
    if (t < 2) {
        float a = clsb[t];
        for (int k = 0; k < NF; ++k) a += z[k] * clsw[t * NF + k];
        out[(size_t)g * 2 + t] = a;
    }
}

extern "C" void kernel_launch(void* const* d_in, const int* in_sizes, int n_in,
                              void* d_out, int out_size, void* d_ws, size_t ws_size,
                              hipStream_t stream) {
    const float* x        = (const float*)d_in[0];
    const int*   eidx     = (const int*)d_in[1];
    const int*   batch    = (const int*)d_in[2];
    const float* c1_src_w = (const float*)d_in[3];
    const float* c1_src_b = (const float*)d_in[4];
    const float* c1_dst_w = (const float*)d_in[5];
    const float* c1_dst_b = (const float*)d_in[6];
    const float* cw1[3] = {(const float*)d_in[7],  (const float*)d_in[13], (const float*)d_in[19]};
    const float* cb1[3] = {(const float*)d_in[8],  (const float*)d_in[14], (const float*)d_in[20]};
    const float* cg[3]  = {(const float*)d_in[9],  (const float*)d_in[15], (const float*)d_in[21]};
    const float* cbe[3] = {(const float*)d_in[10], (const float*)d_in[16], (const float*)d_in[22]};
    const float* cw2[3] = {(const float*)d_in[11], (const float*)d_in[17], (const float*)d_in[23]};
    const float* cb2[3] = {(const float*)d_in[12], (const float*)d_in[18], (const float*)d_in[24]};
    const float* fc1w = (const float*)d_in[25];
    const float* fc1b = (const float*)d_in[26];
    const float* clsw = (const float*)d_in[27];
    const float* clsb = (const float*)d_in[28];

    const int N = in_sizes[0] / XF;
    const int E = in_sizes[1] / 2;
    const int G = out_size / 202;
    const int Mpad = (N + 63) & ~63;
    const int NBK = (N + 255) >> BSHIFT;        // dst buckets
    const int EPB = (E + NBLK_G - 1) / NBLK_G;  // edges per count/scatter block
    const int BM = NBK * NBLK_G;                // bmat elements
    const int NB2 = (BM + 1023) / 1024;         // scan chunks for bmat

    char* p = (char*)d_ws;
    auto alloc = [&](size_t bytes) {
        char* r = p;
        p += (bytes + 255) & ~(size_t)255;
        return r;
    };
    _Float16* h16  = (_Float16*)alloc((size_t)Mpad * 128 * 2);
    _Float16* C16  = (_Float16*)alloc((size_t)Mpad * 128 * 2);
    _Float16* xd16 = (_Float16*)alloc((size_t)Mpad * 128 * 2);
    _Float16* W16  = (_Float16*)alloc((size_t)6 * 32768 * 2);
    int* packed   = (int*)alloc((size_t)E * 4);
    int* esrc     = (int*)alloc((size_t)E * 4);
    int* indptr   = (int*)alloc((size_t)(N + 1) * 4);
    int* bmat     = (int*)alloc((size_t)BM * 4);
    int* blocksum = (int*)alloc((size_t)NB2 * 4);
    int* gcount   = (int*)alloc((size_t)G * 4);
    int* gcur     = (int*)alloc((size_t)G * 4);
    int* gindptr  = (int*)alloc((size_t)(G + 1) * 4);
    int* gnodes   = (int*)alloc((size_t)N * 4);
    float* rbuf   = (float*)alloc((size_t)6 * RCH * G * NF * 4);

    (void)hipMemsetAsync(gcount, 0, (size_t)G * 4, stream);

    // CSR build: count -> chunk-scan -> parallel top scan -> scatter -> finalize
    csr_count_kernel<<<NBLK_G, 256, 0, stream>>>(eidx, bmat, E, NBK, EPB);
    scan1x_kernel<<<NB2, 256, 0, stream>>>(bmat, blocksum, BM);
    small_scan_kernel<<<1, 256, 0, stream>>>(blocksum, 1, blocksum, 1, nullptr, NB2);
    csr_scatter_kernel<<<NBLK_G, 256, 0, stream>>>(eidx, bmat, blocksum, packed, E, NBK, EPB);
    csr_finalize_kernel<<<NBK, 256, 0, stream>>>(bmat, blocksum, packed, indptr, esrc, E, NBK, N);

    // batch-CSR for readout
    gcnt_kernel<<<(N + 255) / 256, 256, 0, stream>>>(batch, gcount, N);
    small_scan_kernel<<<1, 256, 0, stream>>>(gcount, 1, gcur, 1, gindptr, G);
    gfill_kernel<<<(N + 255) / 256, 256, 0, stream>>>(batch, gcur, gnodes, N);

    // weights -> fp16 (padded)
    WArgs wa;
    for (int l = 0; l < 3; ++l) {
        wa.src[l] = cw1[l];     wa.dst[l] = W16 + (size_t)l * 32768;
        wa.src[3 + l] = cw2[l]; wa.dst[3 + l] = W16 + (size_t)(3 + l) * 32768;
    }
    wconv_kernel<<<dim3(128, 6), 256, 0, stream>>>(wa);

    // layer-1 input transforms
    lin10_kernel<<<(N + 63) / 64, 256, 0, stream>>>(x, c1_src_w, c1_src_b,
                                                    c1_dst_w, c1_dst_b, h16, xd16, N);

    for (int l = 0; l < 3; ++l) {
        const _Float16* xdp = (l == 0) ? xd16 : h16;
        if (l == 0)
            agg_kernel<true><<<(N + 1) / 2, 256, 0, stream>>>(h16, xdp, indptr, esrc, C16, N);
        else
            agg_kernel<false><<<(N + 1) / 2, 256, 0, stream>>>(h16, xdp, indptr, esrc, C16, N);
        mlp_fused_kernel<<<Mpad / 64, 256, 0, stream>>>(
            C16, W16 + (size_t)l * 32768, cb1[l], cg[l], cbe[l],
            W16 + (size_t)(3 + l) * 32768, cb2[l], h16, N);
        readout2_kernel<<<dim3(G, RCH), 256, 0, stream>>>(
            h16, gindptr, gnodes,
            rbuf + (size_t)(l * 2) * RCH * G * NF,
            rbuf + (size_t)(l * 2 + 1) * RCH * G * NF, G);
    }

    head_kernel<<<G, 256, 0, stream>>>(rbuf, gindptr, fc1w, fc1b, clsw, clsb, (float*)d_out, G);
    (void)ws_size;
}

// Round 14
// 631.624 us; speedup vs baseline: 1.3697x; 1.3697x over previous
//
#include <hip/hip_runtime.h>
#include <cstdint>
#include <cstddef>

#define XF 10
#define NF 100
#define HF 200
#define BSHIFT 8
#define NBLK_G 512   // blocks for count/scatter passes
#define MAXBK 512    // max dst buckets (N <= 131072)
#define RCH 4        // readout chunks per graph

typedef _Float16 f16x8 __attribute__((ext_vector_type(8)));
typedef _Float16 h2 __attribute__((ext_vector_type(2)));
typedef float f32x4 __attribute__((ext_vector_type(4)));

static __device__ __forceinline__ float bn_scale(float g) {
    return g * 0.9999950000374997f; // 1/sqrt(1 + 1e-5)
}

// ---------------- CSR build: radix partition by dst, no global data atomics ----
__global__ __launch_bounds__(256) void csr_count_kernel(const int* __restrict__ eidx,
                                                        int* __restrict__ bmat,
                                                        int E, int nbk, int epb) {
    __shared__ int hist[MAXBK];
    for (int j = threadIdx.x; j < nbk; j += 256) hist[j] = 0;
    __syncthreads();
    int base = blockIdx.x * epb;
    int end = base + epb; if (end > E) end = E;
    for (int e = base + threadIdx.x; e < end; e += 256) {
        int d = eidx[E + e];
        atomicAdd(&hist[d >> BSHIFT], 1);
    }
    __syncthreads();
    for (int j = threadIdx.x; j < nbk; j += 256)
        bmat[(size_t)j * NBLK_G + blockIdx.x] = hist[j];
}

// chunked exclusive scan of bmat (in place), 1024 elems/chunk; blocksum = chunk totals
__global__ __launch_bounds__(256) void scan1x_kernel(int* __restrict__ a,
                                                     int* __restrict__ blocksum, int n) {
    __shared__ int s[256];
    int t = threadIdx.x;
    int base = blockIdx.x * 1024 + t * 4;
    int v[4]; int tot = 0;
#pragma unroll
    for (int i = 0; i < 4; ++i) {
        v[i] = (base + i < n) ? a[base + i] : 0;
        tot += v[i];
    }
    s[t] = tot;
    __syncthreads();
    for (int off = 1; off < 256; off <<= 1) {
        int add = (t >= off) ? s[t - off] : 0;
        __syncthreads();
        s[t] += add;
        __syncthreads();
    }
    int run = s[t] - tot; // exclusive within chunk
#pragma unroll
    for (int i = 0; i < 4; ++i) {
        if (base + i < n) a[base + i] = run;
        run += v[i];
    }
    if (t == 255) blocksum[blockIdx.x] = s[255];
}

// generic single-block exclusive scan for n<=1024 (strided; in-place safe)
__global__ void small_scan_kernel(const int* __restrict__ in, int in_stride,
                                  int* __restrict__ cur, int cur_stride,
                                  int* __restrict__ indptr, int n) {
    __shared__ int s[256];
    int t = threadIdx.x;
    int base = t * 4;
    int v[4]; int tot = 0;
#pragma unroll
    for (int i = 0; i < 4; ++i) {
        v[i] = (base + i < n) ? in[(base + i) * in_stride] : 0;
        tot += v[i];
    }
    s[t] = tot;
    __syncthreads();
    for (int off = 1; off < 256; off <<= 1) {
        int add = (t >= off) ? s[t - off] : 0;
        __syncthreads();
        s[t] += add;
        __syncthreads();
    }
    int run = s[t] - tot;
#pragma unroll
    for (int i = 0; i < 4; ++i) {
        if (base + i < n) {
            cur[(base + i) * cur_stride] = run;
            run += v[i];
            if (indptr) indptr[base + i + 1] = run;
        }
    }
    if (t == 0 && indptr) indptr[0] = 0;
}

// scatter packed (src | dlocal<<24); cursor = bmat chunk-scan + blocksum offset
__global__ __launch_bounds__(256) void csr_scatter_kernel(const int* __restrict__ eidx,
                                                          const int* __restrict__ bmat,
                                                          const int* __restrict__ blocksum,
                                                          int* __restrict__ packed,
                                                          int E, int nbk, int epb) {
    __shared__ int cur[MAXBK];
    for (int j = threadIdx.x; j < nbk; j += 256) {
        size_t idx = (size_t)j * NBLK_G + blockIdx.x;
        cur[j] = bmat[idx] + blocksum[idx >> 10];
    }
    __syncthreads();
    int base = blockIdx.x * epb;
    int end = base + epb; if (end > E) end = E;
    for (int e = base + threadIdx.x; e < end; e += 256) {
        int s = eidx[e];
        int d = eidx[E + e];
        int p = atomicAdd(&cur[d >> BSHIFT], 1);
        packed[p] = s | ((d & 255) << 24);
    }
}

// one block per bucket -> indptr + esrc (LDS count/scan/cursors only)
__global__ __launch_bounds__(256) void csr_finalize_kernel(const int* __restrict__ bmat,
                                                           const int* __restrict__ blocksum,
                                                           const int* __restrict__ packed,
                                                           int* __restrict__ indptr,
                                                           int* __restrict__ esrc,
                                                           int E, int nbk, int n) {
    __shared__ int cnt[256];
    __shared__ int s[256];
    __shared__ int cur[256];
    int b = blockIdx.x;
    int t = threadIdx.x;
    size_t i0 = (size_t)b * NBLK_G;
    int ebeg = bmat[i0] + blocksum[i0 >> 10];
    int eend = E;
    if (b + 1 < nbk) {
        size_t i1 = (size_t)(b + 1) * NBLK_G;
        eend = bmat[i1] + blocksum[i1 >> 10];
    }
    cnt[t] = 0;
    __syncthreads();
    for (int i = ebeg + t; i < eend; i += 256)
        atomicAdd(&cnt[((unsigned)packed[i]) >> 24], 1);
    __syncthreads();
    int tot = cnt[t];
    s[t] = tot;
    __syncthreads();
    for (int off = 1; off < 256; off <<= 1) {
        int add = (t >= off) ? s[t - off] : 0;
        __syncthreads();
        s[t] += add;
        __syncthreads();
    }
    int off_ex = s[t] - tot; // exclusive
    int node = (b << BSHIFT) + t;
    if (node < n) indptr[node] = ebeg + off_ex;
    if (b == nbk - 1 && t == 0) indptr[n] = E;
    cur[t] = ebeg + off_ex;
    __syncthreads();
    for (int i = ebeg + t; i < eend; i += 256) {
        int p = packed[i];
        int pos = atomicAdd(&cur[((unsigned)p) >> 24], 1);
        esrc[pos] = p & 0xFFFFFF;
    }
}

// batch-CSR: per-graph node lists
__global__ __launch_bounds__(256) void gcnt_kernel(const int* __restrict__ batch,
                                                   int* __restrict__ gcount, int n) {
    int i = blockIdx.x * 256 + threadIdx.x;
    if (i < n) atomicAdd(&gcount[batch[i]], 1);
}

__global__ __launch_bounds__(256) void gfill_kernel(const int* __restrict__ batch,
                                                    int* __restrict__ gcur,
                                                    int* __restrict__ gnodes, int n) {
    int i = blockIdx.x * 256 + threadIdx.x;
    if (i >= n) return;
    int g = batch[i];
    int p = atomicAdd(&gcur[g], 1);
    gnodes[p] = i;
}

// ---------------- weight conversion to fp16, K padded ----------------
struct WArgs {
    const float* src[6];
    _Float16* dst[6];
};
__global__ __launch_bounds__(256) void wconv_kernel(WArgs wa) {
    int w = blockIdx.y;
    int idx = blockIdx.x * 256 + threadIdx.x; // < 32768
    int J, K, j, k;
    if (w < 3) { J = 200; K = 100; j = idx >> 7; k = idx & 127; }
    else       { J = 100; K = 200; j = idx >> 8; k = idx & 255; }
    float v = (j < J && k < K) ? wa.src[w][j * K + k] : 0.f;
    wa.dst[w][idx] = (_Float16)v;
}

// ---------------- layer-1 input linear (10 -> 100) -> fp16, stride 128 ---------
__global__ __launch_bounds__(256) void lin10_kernel(const float* __restrict__ x,
                                                    const float* __restrict__ sw,
                                                    const float* __restrict__ sb,
                                                    const float* __restrict__ dw,
                                                    const float* __restrict__ db,
                                                    _Float16* __restrict__ h16,
                                                    _Float16* __restrict__ xd16, int n_nodes) {
    int t = threadIdx.x;
    int slot = t >> 6, lane = t & 63;
    bool act = lane < 50;
    int f0 = 2 * lane, f1 = f0 + 1;
    float ws0[XF], ws1[XF], wd0[XF], wd1[XF];
    float bs0 = 0.f, bs1 = 0.f, bd0 = 0.f, bd1 = 0.f;
    if (act) {
#pragma unroll
        for (int k = 0; k < XF; ++k) {
            ws0[k] = sw[f0 * XF + k]; ws1[k] = sw[f1 * XF + k];
            wd0[k] = dw[f0 * XF + k]; wd1[k] = dw[f1 * XF + k];
        }
        bs0 = sb[f0]; bs1 = sb[f1]; bd0 = db[f0]; bd1 = db[f1];
    }
    for (int it = 0; it < 16; ++it) {
        int n = blockIdx.x * 64 + it * 4 + slot;
        if (n >= n_nodes) continue;
        float a0 = bs0, a1 = bs1, b0 = bd0, b1 = bd1;
        if (act) {
            const float2* xp = (const float2*)(x + (size_t)n * XF);
            float xv[XF];
#pragma unroll
            for (int k = 0; k < 5; ++k) { float2 v = xp[k]; xv[2 * k] = v.x; xv[2 * k + 1] = v.y; }
#pragma unroll
            for (int k = 0; k < XF; ++k) {
                a0 = fmaf(xv[k], ws0[k], a0);
                a1 = fmaf(xv[k], ws1[k], a1);
                b0 = fmaf(xv[k], wd0[k], b0);
                b1 = fmaf(xv[k], wd1[k], b1);
            }
        } else { a0 = a1 = b0 = b1 = 0.f; }
        ((h2*)(h16 + (size_t)n * 128))[lane] = (h2){(_Float16)a0, (_Float16)a1};
        ((h2*)(xd16 + (size_t)n * 128))[lane] = (h2){(_Float16)b0, (_Float16)b1};
    }
}

// ---------------- softmax aggregation: 1 wave per node, 8-deep prefetch -------
// (round-12 structure — the 2-wave split regressed: doubled per-wave fixed
// cost + sync. Max-free softmax: e = exp2(a*log2e - 40); ratio exact.)
// 256-thread blocks, 4 independent nodes per block (no LDS/sync) for better
// dispatch granularity than 128-thread blocks (occupancy was 69%).
// RELU=false for layers 2-3: input is post-ReLU by construction.
template <bool RELU>
__global__ __launch_bounds__(256) void agg_kernel(const _Float16* __restrict__ h16,
                                                  const _Float16* __restrict__ xd16,
                                                  const int* __restrict__ indptr,
                                                  const int* __restrict__ esrc,
                                                  _Float16* __restrict__ c16, int n_nodes) {
    int n = blockIdx.x * 4 + (threadIdx.x >> 6);
    if (n >= n_nodes) return;
    int lane = threadIdx.x & 63;
    int ln = (lane < 50) ? lane : 0;
    int beg = __builtin_amdgcn_readfirstlane(indptr[n]);
    int end = __builtin_amdgcn_readfirstlane(indptr[n + 1]);
    int deg = end - beg;
    const h2* hb = (const h2*)h16;
    float d0 = 0.f, d1 = 0.f, s0 = 0.f, s1 = 0.f;
    const float L2E = 1.44269504088896f;
    h2 va[8], vb[8];
    if (deg > 0) {
#pragma unroll
        for (int k = 0; k < 8; ++k) {
            int j = (k < deg) ? k : deg - 1;
            unsigned sidx = (unsigned)esrc[beg + j];
            va[k] = hb[(size_t)sidx * 64 + ln];
        }
    }
    for (int r = 0; r < deg; r += 8) {
        if (r + 8 < deg) {
#pragma unroll
            for (int k = 0; k < 8; ++k) {
                int j = (r + 8 + k < deg) ? r + 8 + k : deg - 1;
                unsigned sidx = (unsigned)esrc[beg + j];
                vb[k] = hb[(size_t)sidx * 64 + ln];
            }
        }
        int km = deg - r; if (km > 8) km = 8;
#pragma unroll
        for (int k = 0; k < 8; ++k) {
            if (k < km) {
                float a0 = (float)va[k].x;
                float a1 = (float)va[k].y;
                if (RELU) { a0 = fmaxf(a0, 0.f); a1 = fmaxf(a1, 0.f); }
                a0 += 1e-7f; a1 += 1e-7f;
                float e0 = __builtin_amdgcn_exp2f(fmaf(a0, L2E, -40.f));
                float e1 = __builtin_amdgcn_exp2f(fmaf(a1, L2E, -40.f));
                d0 += e0; s0 = fmaf(e0, a0, s0);
                d1 += e1; s1 = fmaf(e1, a1, s1);
            }
        }
#pragma unroll
        for (int k = 0; k < 8; ++k) va[k] = vb[k];
    }
    const float EPS = 9.094947e-29f; // 1e-16 * 2^-40
    float g0 = s0 / (d0 + EPS);
    float g1 = s1 / (d1 + EPS);
    float o0 = 0.f, o1 = 0.f;
    if (lane < 50) {
        h2 xv = ((const h2*)(xd16 + (size_t)n * 128))[lane];
        o0 = g0 + (float)xv.x;
        o1 = g1 + (float)xv.y;
    }
    ((h2*)(c16 + (size_t)n * 128))[lane] = (h2){(_Float16)o0, (_Float16)o1};
}

// ---------------- fused MLP: h = relu(BN(C@W1^T+b1)) @ W2^T + b2, relu -------
__global__ __launch_bounds__(256, 3) void mlp_fused_kernel(const _Float16* __restrict__ A,
                                                           const _Float16* __restrict__ W1,
                                                           const float* __restrict__ b1v,
                                                           const float* __restrict__ g1v,
                                                           const float* __restrict__ be1v,
                                                           const _Float16* __restrict__ W2,
                                                           const float* __restrict__ b2v,
                                                           _Float16* __restrict__ out16,
                                                           int M) {
    __shared__ _Float16 hh[64][264];
    int wave = threadIdx.x >> 6;
    int lane = threadIdx.x & 63;
    int l15 = lane & 15, quad = lane >> 4;
    long m0 = (long)blockIdx.x * 64;

    // stage 1: HH[64 x 256], wave covers cols [wave*64, wave*64+64)
    const _Float16* aptr = A + (m0 + l15) * 128 + quad * 8;
    const _Float16* w1p  = W1 + (size_t)(wave * 64 + l15) * 128 + quad * 8;
    f32x4 acc[4][4] = {};
#pragma unroll 2
    for (int ks = 0; ks < 4; ++ks) {
        f16x8 bfr[4], afr[4];
#pragma unroll
        for (int ct = 0; ct < 4; ++ct) bfr[ct] = *(const f16x8*)(w1p + (size_t)ct * 16 * 128 + ks * 32);
#pragma unroll
        for (int i = 0; i < 4; ++i) afr[i] = *(const f16x8*)(aptr + (size_t)i * 16 * 128 + ks * 32);
#pragma unroll
        for (int i = 0; i < 4; ++i)
#pragma unroll
            for (int ct = 0; ct < 4; ++ct)
                acc[i][ct] = __builtin_amdgcn_mfma_f32_16x16x32_f16(afr[i], bfr[ct], acc[i][ct], 0, 0, 0);
    }
#pragma unroll
    for (int ct = 0; ct < 4; ++ct) {
        int col = wave * 64 + ct * 16 + l15;
        bool cv = col < HF;
        float bi = cv ? b1v[col] : 0.f;
        float gm = cv ? bn_scale(g1v[col]) : 0.f;
        float bt = cv ? be1v[col] : 0.f;
#pragma unroll
        for (int i = 0; i < 4; ++i)
#pragma unroll
            for (int r = 0; r < 4; ++r) {
                float v = fmaxf((acc[i][ct][r] + bi) * gm + bt, 0.f);
                hh[i * 16 + quad * 4 + r][col] = (_Float16)v;
            }
    }
    __syncthreads();

    // stage 2: out[64 x 128], wave covers cols [wave*32, wave*32+32)
    const _Float16* w2p = W2 + (size_t)(wave * 32 + l15) * 256 + quad * 8;
    f32x4 o[4][2] = {};
#pragma unroll 2
    for (int ks = 0; ks < 8; ++ks) {
        f16x8 bfr[2], afr[4];
#pragma unroll
        for (int ct = 0; ct < 2; ++ct) bfr[ct] = *(const f16x8*)(w2p + (size_t)ct * 16 * 256 + ks * 32);
#pragma unroll
        for (int i = 0; i < 4; ++i) afr[i] = *(const f16x8*)(&hh[i * 16 + l15][quad * 8 + ks * 32]);
#pragma unroll
        for (int i = 0; i < 4; ++i)
#pragma unroll
            for (int ct = 0; ct < 2; ++ct)
                o[i][ct] = __builtin_amdgcn_mfma_f32_16x16x32_f16(afr[i], bfr[ct], o[i][ct], 0, 0, 0);
    }
#pragma unroll
    for (int ct = 0; ct < 2; ++ct) {
        int col = wave * 32 + ct * 16 + l15;
        bool cv = col < NF;
        float bi = cv ? b2v[col] : 0.f;
#pragma unroll
        for (int i = 0; i < 4; ++i)
#pragma unroll
            for (int r = 0; r < 4; ++r) {
                long row = m0 + i * 16 + quad * 4 + r;
                float v = fmaxf(o[i][ct][r] + bi, 0.f);
                if (!cv) v = 0.f;
                if (row < M) out16[row * 128 + col] = (_Float16)v;
            }
    }
}

// ---------------- readout: per-graph gather, 4 chunks/graph -------------------
__global__ __launch_bounds__(256) void readout2_kernel(const _Float16* __restrict__ h16,
                                                       const int* __restrict__ gindptr,
                                                       const int* __restrict__ gnodes,
                                                       float* __restrict__ sumpart,
                                                       float* __restrict__ maxpart, int G) {
    __shared__ float ls[4][128];
    __shared__ float lm[4][128];
    int g = blockIdx.x, ch = blockIdx.y;
    int wave = threadIdx.x >> 6;
    int lane = threadIdx.x & 63;
    int ln = (lane < 50) ? lane : 0;
    int beg = gindptr[g], end = gindptr[g + 1];
    const h2* hb = (const h2*)h16;
    float s0 = 0.f, s1 = 0.f, m0 = 0.f, m1 = 0.f;
    int i = beg + ch * 4 + wave;
    int nd = (i < end) ? gnodes[i] : 0;
    for (; i < end; i += 16) {
        int ndn = (i + 16 < end) ? gnodes[i + 16] : 0;
        h2 v = hb[(size_t)nd * 64 + ln];
        float v0 = (float)v.x, v1 = (float)v.y;
        s0 += v0; s1 += v1;
        m0 = fmaxf(m0, v0); m1 = fmaxf(m1, v1);
        nd = ndn;
    }
    ls[wave][2 * lane] = s0; ls[wave][2 * lane + 1] = s1;
    lm[wave][2 * lane] = m0; lm[wave][2 * lane + 1] = m1;
    __syncthreads();
    int f = threadIdx.x;
    if (f < NF) {
        float ss = ls[0][f] + ls[1][f] + ls[2][f] + ls[3][f];
        float mm = fmaxf(fmaxf(lm[0][f], lm[1][f]), fmaxf(lm[2][f], lm[3][f]));
        sumpart[((size_t)ch * G + g) * NF + f] = ss;
        maxpart[((size_t)ch * G + g) * NF + f] = mm;
    }
}

// ---------------- head: combine partials + encode + fc1 + classifier ----------
__global__ __launch_bounds__(256) void head_kernel(const float* __restrict__ rbuf,
                                                   const int* __restrict__ gindptr,
                                                   const float* __restrict__ fc1w,
                                                   const float* __restrict__ fc1b,
                                                   const float* __restrict__ clsw,
                                                   const float* __restrict__ clsb,
                                                   float* __restrict__ out, int G) {
    __shared__ float enc[HF];
    __shared__ float z[NF];
    int g = blockIdx.x;
    int t = threadIdx.x;
    float ic = 1.f / fmaxf((float)(gindptr[g + 1] - gindptr[g]), 1.f);
    if (t < HF) {
        float e = 0.f;
        if (t < NF) {
#pragma unroll
            for (int l = 0; l < 3; ++l) {
                float s = 0.f;
#pragma unroll
                for (int ch = 0; ch < RCH; ++ch)
                    s += rbuf[(((size_t)(l * 2) * RCH + ch) * G + g) * NF + t];
                e += fmaxf(s * ic, 0.f);
            }
        } else {
            int f = t - NF;
#pragma unroll
            for (int l = 0; l < 3; ++l) {
                float mm = 0.f;
#pragma unroll
                for (int ch = 0; ch < RCH; ++ch)
                    mm = fmaxf(mm, rbuf[(((size_t)(l * 2 + 1) * RCH + ch) * G + g) * NF + f]);
                e += fmaxf(mm, 0.f);
            }
        }
        enc[t] = e;
        out[G * 2 + (size_t)g * HF + t] = e;
    }
    __syncthreads();
    if (t < NF) {
        float a = fc1b[t];
        for (int k = 0; k < HF; ++k) a += enc[k] * fc1w[t * HF + k];
        z[t] = fmaxf(a, 0.f);
    }
    __syncthreads();
    if (t < 2) {
        float a = clsb[t];
        for (int k = 0; k < NF; ++k) a += z[k] * clsw[t * NF + k];
        out[(size_t)g * 2 + t] = a;
    }
}

extern "C" void kernel_launch(void* const* d_in, const int* in_sizes, int n_in,
                              void* d_out, int out_size, void* d_ws, size_t ws_size,
                              hipStream_t stream) {
    const float* x        = (const float*)d_in[0];
    const int*   eidx     = (const int*)d_in[1];
    const int*   batch    = (const int*)d_in[2];
    const float* c1_src_w = (const float*)d_in[3];
    const float* c1_src_b = (const float*)d_in[4];
    const float* c1_dst_w = (const float*)d_in[5];
    const float* c1_dst_b = (const float*)d_in[6];
    const float* cw1[3] = {(const float*)d_in[7],  (const float*)d_in[13], (const float*)d_in[19]};
    const float* cb1[3] = {(const float*)d_in[8],  (const float*)d_in[14], (const float*)d_in[20]};
    const float* cg[3]  = {(const float*)d_in[9],  (const float*)d_in[15], (const float*)d_in[21]};
    const float* cbe[3] = {(const float*)d_in[10], (const float*)d_in[16], (const float*)d_in[22]};
    const float* cw2[3] = {(const float*)d_in[11], (const float*)d_in[17], (const float*)d_in[23]};
    const float* cb2[3] = {(const float*)d_in[12], (const float*)d_in[18], (const float*)d_in[24]};
    const float* fc1w = (const float*)d_in[25];
    const float* fc1b = (const float*)d_in[26];
    const float* clsw = (const float*)d_in[27];
    const float* clsb = (const float*)d_in[28];

    const int N = in_sizes[0] / XF;
    const int E = in_sizes[1] / 2;
    const int G = out_size / 202;
    const int Mpad = (N + 63) & ~63;
    const int NBK = (N + 255) >> BSHIFT;        // dst buckets
    const int EPB = (E + NBLK_G - 1) / NBLK_G;  // edges per count/scatter block
    const int BM = NBK * NBLK_G;                // bmat elements
    const int NB2 = (BM + 1023) / 1024;         // scan chunks for bmat

    char* p = (char*)d_ws;
    auto alloc = [&](size_t bytes) {
        char* r = p;
        p += (bytes + 255) & ~(size_t)255;
        return r;
    };
    _Float16* h16  = (_Float16*)alloc((size_t)Mpad * 128 * 2);
    _Float16* C16  = (_Float16*)alloc((size_t)Mpad * 128 * 2);
    _Float16* xd16 = (_Float16*)alloc((size_t)Mpad * 128 * 2);
    _Float16* W16  = (_Float16*)alloc((size_t)6 * 32768 * 2);
    int* packed   = (int*)alloc((size_t)E * 4);
    int* esrc     = (int*)alloc((size_t)E * 4);
    int* indptr   = (int*)alloc((size_t)(N + 1) * 4);
    int* bmat     = (int*)alloc((size_t)BM * 4);
    int* blocksum = (int*)alloc((size_t)NB2 * 4);
    int* gcount   = (int*)alloc((size_t)G * 4);
    int* gcur     = (int*)alloc((size_t)G * 4);
    int* gindptr  = (int*)alloc((size_t)(G + 1) * 4);
    int* gnodes   = (int*)alloc((size_t)N * 4);
    float* rbuf   = (float*)alloc((size_t)6 * RCH * G * NF * 4);

    (void)hipMemsetAsync(gcount, 0, (size_t)G * 4, stream);

    // CSR build: count -> chunk-scan -> parallel top scan -> scatter -> finalize
    csr_count_kernel<<<NBLK_G, 256, 0, stream>>>(eidx, bmat, E, NBK, EPB);
    scan1x_kernel<<<NB2, 256, 0, stream>>>(bmat, blocksum, BM);
    small_scan_kernel<<<1, 256, 0, stream>>>(blocksum, 1, blocksum, 1, nullptr, NB2);
    csr_scatter_kernel<<<NBLK_G, 256, 0, stream>>>(eidx, bmat, blocksum, packed, E, NBK, EPB);
    csr_finalize_kernel<<<NBK, 256, 0, stream>>>(bmat, blocksum, packed, indptr, esrc, E, NBK, N);

    // batch-CSR for readout
    gcnt_kernel<<<(N + 255) / 256, 256, 0, stream>>>(batch, gcount, N);
    small_scan_kernel<<<1, 256, 0, stream>>>(gcount, 1, gcur, 1, gindptr, G);
    gfill_kernel<<<(N + 255) / 256, 256, 0, stream>>>(batch, gcur, gnodes, N);

    // weights -> fp16 (padded)
    WArgs wa;
    for (int l = 0; l < 3; ++l) {
        wa.src[l] = cw1[l];     wa.dst[l] = W16 + (size_t)l * 32768;
        wa.src[3 + l] = cw2[l]; wa.dst[3 + l] = W16 + (size_t)(3 + l) * 32768;
    }
    wconv_kernel<<<dim3(128, 6), 256, 0, stream>>>(wa);

    // layer-1 input transforms
    lin10_kernel<<<(N + 63) / 64, 256, 0, stream>>>(x, c1_src_w, c1_src_b,
                                                    c1_dst_w, c1_dst_b, h16, xd16, N);

    for (int l = 0; l < 3; ++l) {
        const _Float16* xdp = (l == 0) ? xd16 : h16;
        if (l == 0)
            agg_kernel<true><<<(N + 3) / 4, 256, 0, stream>>>(h16, xdp, indptr, esrc, C16, N);
        else
            agg_kernel<false><<<(N + 3) / 4, 256, 0, stream>>>(h16, xdp, indptr, esrc, C16, N);
        mlp_fused_kernel<<<Mpad / 64, 256, 0, stream>>>(
            C16, W16 + (size_t)l * 32768, cb1[l], cg[l], cbe[l],
            W16 + (size_t)(3 + l) * 32768, cb2[l], h16, N);
        readout2_kernel<<<dim3(G, RCH), 256, 0, stream>>>(
            h16, gindptr, gnodes,
            rbuf + (size_t)(l * 2) * RCH * G * NF,
            rbuf + (size_t)(l * 2 + 1) * RCH * G * NF, G);
    }

    head_kernel<<<G, 256, 0, stream>>>(rbuf, gindptr, fc1w, fc1b, clsw, clsb, (float*)d_out, G);
    (void)ws_size;
}